// Round 8
// baseline (386.206 us; speedup 1.0000x reference)
//
#include <hip/hip_runtime.h>
#include <stdint.h>

typedef __attribute__((ext_vector_type(8))) short bf16x8;
typedef __attribute__((ext_vector_type(4))) float f32x4;
typedef __attribute__((ext_vector_type(2))) unsigned int u32x2;
typedef unsigned short u16;
typedef unsigned int u32;

#define MFMA16(a, b, c) __builtin_amdgcn_mfma_f32_16x16x32_bf16((a), (b), (c), 0, 0, 0)
// Builtin barrier: NO implicit waitcnt, NO memory clobber.
#define SBAR() __builtin_amdgcn_s_barrier()
#define WAITV(N) asm volatile("s_waitcnt vmcnt(" #N ")")

__device__ __forceinline__ u16 f2bf(float f) {
  union { float f; u32 u; } c; c.f = f;
  u32 u = c.u;
  return (u16)((u + 0x7FFFu + ((u >> 16) & 1u)) >> 16);
}

__device__ __forceinline__ float bf2f(u16 h) {
  union { u32 u; float f; } c;
  c.u = ((u32)h) << 16;
  return c.f;
}

__device__ __forceinline__ void gll16(const void* g, void* l) {
  __builtin_amdgcn_global_load_lds((__attribute__((address_space(1))) void*)(g),
                                   (__attribute__((address_space(3))) void*)(l),
                                   16, 0, 0);
}

// ---------------- prep: cast x to bf16 ----------------
__global__ __launch_bounds__(256) void cast_k(const float* __restrict__ x, u16* __restrict__ xb) {
  int idx = blockIdx.x * 256 + threadIdx.x;
#pragma unroll
  for (int it = 0; it < 4; it++) {
    size_t i = (size_t)idx + (size_t)it * 1048576;
    float4 v = ((const float4*)x)[i];
    u32x2 p;
    p.x = (u32)f2bf(v.x) | ((u32)f2bf(v.y) << 16);
    p.y = (u32)f2bf(v.z) | ((u32)f2bf(v.w) << 16);
    ((u32x2*)xb)[i] = p;
  }
}

// ---------------- prep: weight transpose to [N][K] bf16 ----------------
__global__ __launch_bounds__(256) void wT_k(const float* __restrict__ Wq, const float* __restrict__ Wk,
                                            const float* __restrict__ Wv, const float* __restrict__ Wo,
                                            u16* __restrict__ wqkvT, u16* __restrict__ woT) {
  __shared__ float t[32][33];
  int which = blockIdx.z;
  const float* W = (which == 0) ? Wq : (which == 1) ? Wk : (which == 2) ? Wv : Wo;
  int k0 = blockIdx.y * 32, n0 = blockIdx.x * 32;
  int c = threadIdx.x & 31, r8 = threadIdx.x >> 5;
#pragma unroll
  for (int rr = 0; rr < 32; rr += 8)
    t[r8 + rr][c] = W[(size_t)(k0 + r8 + rr) * 1024 + n0 + c];
  __syncthreads();
  u16* outp = (which < 3) ? (wqkvT + (size_t)which * 1048576) : woT;
#pragma unroll
  for (int rr = 0; rr < 32; rr += 8)
    outp[(size_t)(n0 + r8 + rr) * 1024 + k0 + c] = f2bf(t[c][r8 + rr]);
}

// ---------------- GEMM: 256x256 tile, BK=64, loose 2-barrier counted-vmcnt schedule ----------
// (R3/R6-measured structure: 113.3 us gemm<0>, MfmaUtil 39%, 0 bank conflicts. DO NOT TOUCH:
// 5 schedule variants (8-barrier, reg-pipeline, 1-barrier 3-buf) all measured worse.)
// 512 threads = 8 waves (2M x 4N); per-wave output 128x64 (acc[8][4]).
// LDS 128 KiB: As/Bs[2 dbuf][2 half][128*64] bf16, XOR-swizzled (slot ^= row&7, 16B slots).
__device__ __forceinline__ void stage_half(const u16* g, u16* l, int tid) {
  gll16(g, l + tid * 8);
  gll16(g + 65536, l + 4096 + tid * 8);  // +64 rows
}

__device__ __forceinline__ bf16x8 fragld(const u16* h, int r, int slot) {
  return *(const bf16x8*)(h + r * 64 + ((slot ^ (r & 7)) << 3));
}

template <int MODE>
__global__ __launch_bounds__(512, 2) void gemm_k(
    const u16* __restrict__ A, const u16* __restrict__ Bt,
    const float* __restrict__ b0, const float* __restrict__ b1, const float* __restrict__ b2,
    u16* __restrict__ q_o, u16* __restrict__ k_o, u16* __restrict__ vt_o,
    const u16* __restrict__ xres, u16* __restrict__ y_o) {
  __shared__ u16 As[2][2][8192];
  __shared__ u16 Bs[2][2][8192];
  const int tid = threadIdx.x;
  const int wave = tid >> 6, lane = tid & 63;
  const int quad = lane >> 4, l16 = lane & 15;
  const int wr = wave >> 2, wc = wave & 3;
  const int bm = blockIdx.x, bn = blockIdx.y;
  const size_t arow = (size_t)bm * 256;
  const size_t brow = (size_t)bn * 256;

  const int r0 = tid >> 3;
  const int s8 = tid & 7;
  const int swz = (s8 ^ (r0 & 7)) << 3;  // inverse-swizzled source column
  const u16* gA = A + (arow + r0) * 1024 + swz;
  const u16* gB = Bt + (brow + r0) * 1024 + swz;

  f32x4 zero = {0.f, 0.f, 0.f, 0.f};
  f32x4 acc[8][4];
#pragma unroll
  for (int i = 0; i < 8; i++)
#pragma unroll
    for (int j = 0; j < 4; j++) acc[i][j] = zero;

  // prologue: T0 fully + T1.B halves; wait all but the 2 newest half-tiles (4 instrs)
  stage_half(gA, &As[0][0][0], tid);
  stage_half(gA + 131072, &As[0][1][0], tid);
  stage_half(gB, &Bs[0][0][0], tid);
  stage_half(gB + 131072, &Bs[0][1][0], tid);
  stage_half(gB + 64, &Bs[1][0][0], tid);
  stage_half(gB + 131072 + 64, &Bs[1][1][0], tid);
  WAITV(4);
  SBAR();

  const int bno = (wc & 1) * 64;
#pragma unroll 2
  for (int t = 0; t < 16; ++t) {
    const int cb = t & 1, nb = cb ^ 1;
    const u16* Ah = &As[cb][wr][0];
    const u16* Bh = &Bs[cb][wc >> 1][0];

    // all B frags for this tile (LDS reads of Bs[cb] happen only here)
    bf16x8 bfr[4][2];
#pragma unroll
    for (int n = 0; n < 4; n++)
#pragma unroll
      for (int ks = 0; ks < 2; ks++)
        bfr[n][ks] = fragld(Bh, bno + n * 16 + l16, ks * 4 + quad);

    // ---- first half: m0..3; stage (t+1).A ----
    {
      bf16x8 am[2][2];
#pragma unroll
      for (int m = 0; m < 2; m++)
#pragma unroll
        for (int ks = 0; ks < 2; ks++)
          am[m][ks] = fragld(Ah, m * 16 + l16, ks * 4 + quad);
      if (t < 15) stage_half(gA + (t + 1) * 64, &As[nb][0][0], tid);
      __builtin_amdgcn_s_setprio(1);
#pragma unroll
      for (int ks = 0; ks < 2; ks++)
#pragma unroll
        for (int m = 0; m < 2; m++)
#pragma unroll
          for (int n = 0; n < 4; n++) acc[m][n] = MFMA16(am[m][ks], bfr[n][ks], acc[m][n]);
      __builtin_amdgcn_s_setprio(0);
    }
    {
      bf16x8 am[2][2];
#pragma unroll
      for (int m = 0; m < 2; m++)
#pragma unroll
        for (int ks = 0; ks < 2; ks++)
          am[m][ks] = fragld(Ah, 32 + m * 16 + l16, ks * 4 + quad);
      if (t < 15) stage_half(gA + 131072 + (t + 1) * 64, &As[nb][1][0], tid);
      __builtin_amdgcn_s_setprio(1);
#pragma unroll
      for (int ks = 0; ks < 2; ks++)
#pragma unroll
        for (int m = 0; m < 2; m++)
#pragma unroll
          for (int n = 0; n < 4; n++) acc[2 + m][n] = MFMA16(am[m][ks], bfr[n][ks], acc[2 + m][n]);
      __builtin_amdgcn_s_setprio(0);
    }

    // mid-tile fence: all waves' B-reads served before Bs[cb] overwrite below.
    SBAR();
    __builtin_amdgcn_sched_barrier(0);

    // ---- second half: m4..7; stage (t+2).B into Bs[cb] ----
    {
      bf16x8 am[2][2];
#pragma unroll
      for (int m = 0; m < 2; m++)
#pragma unroll
        for (int ks = 0; ks < 2; ks++)
          am[m][ks] = fragld(Ah, 64 + m * 16 + l16, ks * 4 + quad);
      if (t < 14) stage_half(gB + (t + 2) * 64, &Bs[cb][0][0], tid);
      __builtin_amdgcn_s_setprio(1);
#pragma unroll
      for (int ks = 0; ks < 2; ks++)
#pragma unroll
        for (int m = 0; m < 2; m++)
#pragma unroll
          for (int n = 0; n < 4; n++) acc[4 + m][n] = MFMA16(am[m][ks], bfr[n][ks], acc[4 + m][n]);
      __builtin_amdgcn_s_setprio(0);
    }
    {
      bf16x8 am[2][2];
#pragma unroll
      for (int m = 0; m < 2; m++)
#pragma unroll
        for (int ks = 0; ks < 2; ks++)
          am[m][ks] = fragld(Ah, 96 + m * 16 + l16, ks * 4 + quad);
      if (t < 14) stage_half(gB + 131072 + (t + 2) * 64, &Bs[cb][1][0], tid);
      __builtin_amdgcn_s_setprio(1);
#pragma unroll
      for (int ks = 0; ks < 2; ks++)
#pragma unroll
        for (int m = 0; m < 2; m++)
#pragma unroll
          for (int n = 0; n < 4; n++) acc[6 + m][n] = MFMA16(am[m][ks], bfr[n][ks], acc[6 + m][n]);
      __builtin_amdgcn_s_setprio(0);
    }

    // K-tile boundary: next tile's A0,A1,B0,B1 landed; (t+2).B halves may stay in flight
    if (t < 14) {
      WAITV(4);
    } else if (t == 14) {
      WAITV(0);
    }
    SBAR();
  }

  if (MODE == 0) {
#pragma unroll
    for (int i = 0; i < 8; i++) {
      const int m0 = bm * 256 + wr * 128 + i * 16 + quad * 4;  // 4 consecutive tokens
      const int b = m0 >> 13, l0 = m0 & 8191;
      const int nch = l0 >> 8, c0 = l0 & 255;
#pragma unroll
      for (int j = 0; j < 4; j++) {
        const int n_g = bn * 256 + wc * 64 + j * 16 + l16;
        const int sec = n_g >> 10, e = n_g & 1023;
        const float* bias = (sec == 0) ? b0 : ((sec == 1) ? b1 : b2);
        const float be = bias[e];
        float v4[4];
#pragma unroll
        for (int r = 0; r < 4; r++) {
          float v = acc[i][j][r] + be;
          if (sec < 2) v = (v > 0.f) ? (v + 1.f) : __expf(v);
          v4[r] = v;
        }
        const int h = e >> 6, d = e & 63;
        const int bh = b * 16 + h;
        if (sec == 2) {
          u32x2 p;
          p.x = (u32)f2bf(v4[0]) | ((u32)f2bf(v4[1]) << 16);
          p.y = (u32)f2bf(v4[2]) | ((u32)f2bf(v4[3]) << 16);
          *(u32x2*)&vt_o[(((size_t)(bh * 32 + nch)) * 64 + d) * 256 + c0] = p;
        } else {
          u16* dst = (sec == 0) ? q_o : k_o;
          const size_t tb = (((size_t)bh * 8192 + l0) << 6) + d;
#pragma unroll
          for (int r = 0; r < 4; r++) dst[tb + (size_t)r * 64] = f2bf(v4[r]);
        }
      }
    }
  } else {
#pragma unroll
    for (int i = 0; i < 8; i++) {
#pragma unroll
      for (int j = 0; j < 4; j++) {
#pragma unroll
        for (int r = 0; r < 4; r++) {
          int m_g = bm * 256 + wr * 128 + i * 16 + quad * 4 + r;
          int n_g = bn * 256 + wc * 64 + j * 16 + l16;
          float v = acc[i][j][r] + b0[n_g] + bf2f(xres[(size_t)m_g * 1024 + n_g]);
          y_o[(size_t)m_g * 1024 + n_g] = f2bf(v);
        }
      }
    }
  }
}

// ---------------- phase A: per-chunk S^T = v^T k ([d2][d1]) and z = colsum k ----------------
__global__ __launch_bounds__(256, 2) void phaseA_k(const u16* __restrict__ kb, const u16* __restrict__ vt,
                                                   float* __restrict__ ST, float* __restrict__ zc) {
  __shared__ u16 kT[64 * 264];  // stride 264: rows 16B-aligned, b128 bank-spread (132 % 32 == 4)
  const int tid = threadIdx.x;
  const int wave = tid >> 6, lane = tid & 63;
  const int quad = lane >> 4, l16 = lane & 15;
  const int wr = wave >> 1, wc = wave & 1;
  const int bhn = blockIdx.x;
  const u16* kc = kb + (size_t)bhn * 16384;   // natural [c][d]
  const u16* vtc = vt + (size_t)bhn * 16384;  // transposed [d][c]

#pragma unroll
  for (int t = 0; t < 2; t++) {
    const int dblk = wave + 4 * t;
#pragma unroll
    for (int itc = 0; itc < 4; itc++) {
      const int c = itc * 64 + lane;
      bf16x8 kv = *(const bf16x8*)&kc[c * 64 + dblk * 8];
#pragma unroll
      for (int j = 0; j < 8; j++) kT[(dblk * 8 + j) * 264 + c] = (u16)kv[j];
    }
  }
  __syncthreads();

  f32x4 zero = {0.f, 0.f, 0.f, 0.f};
  f32x4 t4[2][2];
  f32x4 za[2];
#pragma unroll
  for (int i = 0; i < 2; i++) {
    za[i] = zero;
#pragma unroll
    for (int j = 0; j < 2; j++) t4[i][j] = zero;
  }
  bf16x8 ones;
#pragma unroll
  for (int j = 0; j < 8; j++) ones[j] = (short)0x3F80;

#pragma unroll
  for (int ks = 0; ks < 8; ks++) {
    bf16x8 av[2], bk2[2];
#pragma unroll
    for (int t = 0; t < 2; t++) av[t] = *(const bf16x8*)&vtc[(wr * 32 + t * 16 + l16) * 256 + ks * 32 + quad * 8];
#pragma unroll
    for (int t = 0; t < 2; t++) bk2[t] = *(const bf16x8*)&kT[(wc * 32 + t * 16 + l16) * 264 + ks * 32 + quad * 8];
#pragma unroll
    for (int i = 0; i < 2; i++)
#pragma unroll
      for (int j = 0; j < 2; j++) t4[i][j] = MFMA16(av[i], bk2[j], t4[i][j]);
    if (wr == 0) {
#pragma unroll
      for (int j = 0; j < 2; j++) za[j] = MFMA16(ones, bk2[j], za[j]);
    }
  }
  float* Sg = ST + (size_t)bhn * 4096;
#pragma unroll
  for (int i = 0; i < 2; i++)
#pragma unroll
    for (int j = 0; j < 2; j++)
#pragma unroll
      for (int r = 0; r < 4; r++)
        Sg[(wr * 32 + i * 16 + quad * 4 + r) * 64 + wc * 32 + j * 16 + l16] = t4[i][j][r];
  if (wr == 0 && quad == 0) {
#pragma unroll
    for (int j = 0; j < 2; j++) zc[(size_t)bhn * 64 + wc * 32 + j * 16 + l16] = za[j][0];
  }
}

// ---------------- phase B: exclusive prefix over chunks ----------------
__global__ __launch_bounds__(256) void phaseB_k(const float* __restrict__ ST, const float* __restrict__ zc,
                                                u16* __restrict__ STp, u16* __restrict__ zp) {
  const int blk = blockIdx.x, tid = threadIdx.x;
  if (blk < 512) {
    const int bh = blk >> 4;
    const int e = ((blk & 15) << 8) + tid;
    const size_t base = (size_t)bh * 32 * 4096 + e;
    float run = 0.f;
#pragma unroll
    for (int n = 0; n < 32; n++) {
      float v = ST[base + (size_t)n * 4096];
      STp[base + (size_t)n * 4096] = f2bf(run);
      run += v;
    }
  } else {
    const int idx = (blk - 512) * 256 + tid;
    const int bh = idx >> 6, d = idx & 63;
    const size_t zb = (size_t)bh * 2048 + d;
    float run = 0.f;
#pragma unroll
    for (int n = 0; n < 32; n++) {
      float v = zc[zb + n * 64];
      zp[zb + n * 64] = f2bf(run);
      run += v;
    }
  }
}

// ---------------- phase C: one wave = one (chunk, band) -- HW-scheduler load balancing ------
// 4096 blocks x 64 threads: blk = bhn*4 + band (band interleaved for dispatch mixing).
// Band b does b+1 slabs (1/2/3/4); short blocks backfill around long ones, so the
// triangular imbalance costs block-slots, not wave-slots. Work per wave identical to the
// R3 form (q-load, S-prefix, slabs) -- zero added redundancy; P was already wave-private.
__global__ __launch_bounds__(64) void phaseC_k(const u16* __restrict__ qb, const u16* __restrict__ kb,
                                               const u16* __restrict__ vt, const u16* __restrict__ STp,
                                               const u16* __restrict__ zp, u16* __restrict__ ao) {
  __shared__ u16 P[64 * 72];
  const int lane = threadIdx.x;
  const int quad = lane >> 4, l16 = lane & 15;
  const int blk = blockIdx.x;
  const int band = blk & 3;
  const int bhn = blk >> 2;
  const int bh = bhn >> 5, n = bhn & 31;
  const int b = bh >> 4, h = bh & 15;
  const size_t cbase = (size_t)bhn * 16384;
  const u16* qc = qb + cbase;
  const u16* kc = kb + cbase;
  const u16* vtc = vt + cbase;
  const u16* STg = STp + (size_t)bhn * 4096;
  const u16* zg = zp + (size_t)bhn * 64;

  f32x4 zero = {0.f, 0.f, 0.f, 0.f};
  f32x4 num[4][4];
  f32x4 den[4];
#pragma unroll
  for (int i = 0; i < 4; i++) {
    den[i] = zero;
#pragma unroll
    for (int j = 0; j < 4; j++) num[i][j] = zero;
  }
  bf16x8 ones;
#pragma unroll
  for (int j = 0; j < 8; j++) ones[j] = (short)0x3F80;

  // preload q fragments for this band's 64-row slice
  bf16x8 aq[4][2];
#pragma unroll
  for (int i = 0; i < 4; i++)
#pragma unroll
    for (int ks = 0; ks < 2; ks++)
      aq[i][ks] = *(const bf16x8*)&qc[(band * 64 + i * 16 + l16) * 64 + ks * 32 + quad * 8];

  // num += q @ S_prefix ; den += q . z_prefix (z replicated across B cols)
#pragma unroll
  for (int ks = 0; ks < 2; ks++) {
    bf16x8 bz = *(const bf16x8*)&zg[ks * 32 + quad * 8];
    bf16x8 bs[4];
#pragma unroll
    for (int j = 0; j < 4; j++) bs[j] = *(const bf16x8*)&STg[(j * 16 + l16) * 64 + ks * 32 + quad * 8];
#pragma unroll
    for (int i = 0; i < 4; i++) {
      den[i] = MFMA16(aq[i][ks], bz, den[i]);
#pragma unroll
      for (int j = 0; j < 4; j++) num[i][j] = MFMA16(aq[i][ks], bs[j], num[i][j]);
    }
  }

  for (int cc = 0; cc <= band; cc++) {  // slabs with cc > band are fully masked
    bf16x8 bkf[2][4];
#pragma unroll
    for (int ks = 0; ks < 2; ks++)
#pragma unroll
      for (int j = 0; j < 4; j++)
        bkf[ks][j] = *(const bf16x8*)&kc[(cc * 64 + j * 16 + l16) * 64 + ks * 32 + quad * 8];
#pragma unroll
    for (int i = 0; i < 4; i++) {
      f32x4 sc4[4];
#pragma unroll
      for (int j = 0; j < 4; j++) sc4[j] = zero;
#pragma unroll
      for (int ks = 0; ks < 2; ks++)
#pragma unroll
        for (int j = 0; j < 4; j++) sc4[j] = MFMA16(aq[i][ks], bkf[ks][j], sc4[j]);
#pragma unroll
      for (int j = 0; j < 4; j++) {
#pragma unroll
        for (int r = 0; r < 4; r++) {
          int row = band * 64 + i * 16 + quad * 4 + r;
          int col = cc * 64 + j * 16 + l16;
          float v = (col <= row) ? sc4[j][r] : 0.f;
          P[(i * 16 + quad * 4 + r) * 72 + j * 16 + l16] = f2bf(v);
        }
      }
    }
    bf16x8 bvf[2][4];
#pragma unroll
    for (int ks2 = 0; ks2 < 2; ks2++)
#pragma unroll
      for (int j = 0; j < 4; j++)
        bvf[ks2][j] = *(const bf16x8*)&vtc[(j * 16 + l16) * 256 + cc * 64 + ks2 * 32 + quad * 8];
#pragma unroll
    for (int i = 0; i < 4; i++) {
#pragma unroll
      for (int ks2 = 0; ks2 < 2; ks2++) {
        bf16x8 ap = *(const bf16x8*)&P[(i * 16 + l16) * 72 + ks2 * 32 + quad * 8];
#pragma unroll
        for (int j = 0; j < 4; j++) num[i][j] = MFMA16(ap, bvf[ks2][j], num[i][j]);
        den[i] = MFMA16(ap, ones, den[i]);
      }
    }
  }

  // epilogue: divide and scatter to attnout [B,L,H,D] bf16
#pragma unroll
  for (int i = 0; i < 4; i++)
#pragma unroll
    for (int j = 0; j < 4; j++)
#pragma unroll
      for (int r = 0; r < 4; r++) {
        int row = band * 64 + i * 16 + quad * 4 + r;
        int col = j * 16 + l16;
        float o = num[i][j][r] / (den[i][r] + 1e-6f);
        int l = n * 256 + row;
        ao[(((size_t)b * 8192 + l) * 16 + h) * 64 + col] = f2bf(o);
      }
}

// ---------------- LayerNorm (bf16 in, f32 out) ----------------
__global__ __launch_bounds__(256) void ln_k(const u16* __restrict__ y, const float* __restrict__ gamma,
                                            const float* __restrict__ beta, float* __restrict__ o) {
  int row = blockIdx.x, tid = threadIdx.x;
  u32x2 pv = ((const u32x2*)(y + (size_t)row * 1024))[tid];
  float vx = bf2f((u16)(pv.x & 0xFFFF)), vy = bf2f((u16)(pv.x >> 16));
  float vz = bf2f((u16)(pv.y & 0xFFFF)), vw = bf2f((u16)(pv.y >> 16));
  float s = vx + vy + vz + vw;
  float s2 = vx * vx + vy * vy + vz * vz + vw * vw;
#pragma unroll
  for (int off = 32; off; off >>= 1) {
    s += __shfl_down(s, off, 64);
    s2 += __shfl_down(s2, off, 64);
  }
  __shared__ float red[8];
  int wave = tid >> 6, lane = tid & 63;
  if (lane == 0) { red[wave] = s; red[4 + wave] = s2; }
  __syncthreads();
  s = red[0] + red[1] + red[2] + red[3];
  s2 = red[4] + red[5] + red[6] + red[7];
  float mu = s * 0.0009765625f;
  float var = s2 * 0.0009765625f - mu * mu;
  float inv = rsqrtf(var + 1e-5f);
  float4 g = ((const float4*)gamma)[tid];
  float4 bb = ((const float4*)beta)[tid];
  float4 ov;
  ov.x = g.x * (vx - mu) * inv + bb.x;
  ov.y = g.y * (vy - mu) * inv + bb.y;
  ov.z = g.z * (vz - mu) * inv + bb.z;
  ov.w = g.w * (vw - mu) * inv + bb.w;
  ((float4*)(o + (size_t)row * 1024))[tid] = ov;
}

extern "C" void kernel_launch(void* const* d_in, const int* in_sizes, int n_in,
                              void* d_out, int out_size, void* d_ws, size_t ws_size,
                              hipStream_t stream) {
  const float* x = (const float*)d_in[0];
  const float* Wq = (const float*)d_in[1];
  const float* bq = (const float*)d_in[2];
  const float* Wk = (const float*)d_in[3];
  const float* bk = (const float*)d_in[4];
  const float* Wv = (const float*)d_in[5];
  const float* bv = (const float*)d_in[6];
  const float* Wo = (const float*)d_in[7];
  const float* bo = (const float*)d_in[8];
  const float* gamma = (const float*)d_in[9];
  const float* beta = (const float*)d_in[10];

  char* ws = (char*)d_ws;
  u16* xb = (u16*)(ws + 0);                  // 33 MB (alive through gemm1: residual)
  u16* qb = (u16*)(ws + 33554432);           // 33 MB (dead after phaseC)
  u16* kb = (u16*)(ws + 67108864);           // 33 MB (dead after phaseC)
  u16* attno = (u16*)(ws + 100663296);       // 33 MB (phaseC out, gemm1 in)
  u16* vt = (u16*)(ws + 134217728);          // 33 MB (dead after phaseC)
  u16* wqkvT = (u16*)(ws + 167772160);       // 6 MB
  u16* woT = (u16*)(ws + 174063616);         // 2 MB
  float* SchT = (float*)(ws + 176160768);    // 16 MB
  float* zch = (float*)(ws + 192937984);     // 256 KB
  u16* STp = (u16*)(ws + 193200128);         // 8 MB
  u16* zp = (u16*)(ws + 201588736);          // 128 KB -> end 201719808
  u16* ypre = qb;                            // bf16 33 MB over qb (dead after phaseC)

  cast_k<<<4096, 256, 0, stream>>>(x, xb);
  wT_k<<<dim3(32, 32, 4), 256, 0, stream>>>(Wq, Wk, Wv, Wo, wqkvT, woT);
  gemm_k<0><<<dim3(64, 12), 512, 0, stream>>>(xb, wqkvT, bq, bk, bv, qb, kb, vt, nullptr, nullptr);
  phaseA_k<<<1024, 256, 0, stream>>>(kb, vt, SchT, zch);
  phaseB_k<<<520, 256, 0, stream>>>(SchT, zch, STp, zp);
  phaseC_k<<<4096, 64, 0, stream>>>(qb, kb, vt, STp, zp, attno);
  gemm_k<1><<<dim3(64, 4), 512, 0, stream>>>(attno, woT, bo, nullptr, nullptr, nullptr, nullptr, nullptr, xb,
                                             ypre);
  ln_k<<<16384, 256, 0, stream>>>(ypre, gamma, beta, (float*)d_out);
}

// Round 9
// 360.139 us; speedup vs baseline: 1.0724x; 1.0724x over previous
//
#include <hip/hip_runtime.h>
#include <stdint.h>

typedef __attribute__((ext_vector_type(8))) short bf16x8;
typedef __attribute__((ext_vector_type(4))) float f32x4;
typedef __attribute__((ext_vector_type(2))) unsigned int u32x2;
typedef unsigned short u16;
typedef unsigned int u32;

#define MFMA16(a, b, c) __builtin_amdgcn_mfma_f32_16x16x32_bf16((a), (b), (c), 0, 0, 0)
// Builtin barrier: NO implicit waitcnt, NO memory clobber.
#define SBAR() __builtin_amdgcn_s_barrier()
#define WAITV(N) asm volatile("s_waitcnt vmcnt(" #N ")")

__device__ __forceinline__ u16 f2bf(float f) {
  union { float f; u32 u; } c; c.f = f;
  u32 u = c.u;
  return (u16)((u + 0x7FFFu + ((u >> 16) & 1u)) >> 16);
}

__device__ __forceinline__ float bf2f(u16 h) {
  union { u32 u; float f; } c;
  c.u = ((u32)h) << 16;
  return c.f;
}

__device__ __forceinline__ void gll16(const void* g, void* l) {
  __builtin_amdgcn_global_load_lds((__attribute__((address_space(1))) void*)(g),
                                   (__attribute__((address_space(3))) void*)(l),
                                   16, 0, 0);
}

// ---------------- prep (fused): cast x to bf16 + weight transpose ----------------
// blocks 0..4095: cast 1024 float4 each. blocks 4096..8191: 32x32 transpose tiles of
// the 4 weight matrices (independent work, merged to save a dispatch).
__global__ __launch_bounds__(256) void prep_k(const float* __restrict__ x, u16* __restrict__ xb,
                                              const float* __restrict__ Wq, const float* __restrict__ Wk,
                                              const float* __restrict__ Wv, const float* __restrict__ Wo,
                                              u16* __restrict__ wqkvT, u16* __restrict__ woT) {
  __shared__ float t[32][33];
  const int blk = blockIdx.x;
  if (blk < 4096) {
    int idx = blk * 256 + threadIdx.x;
#pragma unroll
    for (int it = 0; it < 4; it++) {
      size_t i = (size_t)idx + (size_t)it * 1048576;
      float4 v = ((const float4*)x)[i];
      u32x2 p;
      p.x = (u32)f2bf(v.x) | ((u32)f2bf(v.y) << 16);
      p.y = (u32)f2bf(v.z) | ((u32)f2bf(v.w) << 16);
      ((u32x2*)xb)[i] = p;
    }
  } else {
    const int wblk = blk - 4096;
    const int which = wblk >> 10;
    const int rem = wblk & 1023;
    const int k0 = (rem >> 5) * 32, n0 = (rem & 31) * 32;
    const float* W = (which == 0) ? Wq : (which == 1) ? Wk : (which == 2) ? Wv : Wo;
    int c = threadIdx.x & 31, r8 = threadIdx.x >> 5;
#pragma unroll
    for (int rr = 0; rr < 32; rr += 8)
      t[r8 + rr][c] = W[(size_t)(k0 + r8 + rr) * 1024 + n0 + c];
    __syncthreads();
    u16* outp = (which < 3) ? (wqkvT + (size_t)which * 1048576) : woT;
#pragma unroll
    for (int rr = 0; rr < 32; rr += 8)
      outp[(size_t)(n0 + r8 + rr) * 1024 + k0 + c] = f2bf(t[c][r8 + rr]);
  }
}

// ---------------- GEMM: 256x256 tile, BK=64, loose 2-barrier counted-vmcnt schedule ----------
// (R3/R6/R8-measured structure: ~114 us gemm<0>, MfmaUtil 39%, 0 bank conflicts. FROZEN:
// 5 schedule variants (8-barrier, reg-pipeline, 1-barrier 3-buf) all measured worse.)
// 512 threads = 8 waves (2M x 4N); per-wave output 128x64 (acc[8][4]).
// LDS 128 KiB: As/Bs[2 dbuf][2 half][128*64] bf16, XOR-swizzled (slot ^= row&7, 16B slots).
__device__ __forceinline__ void stage_half(const u16* g, u16* l, int tid) {
  gll16(g, l + tid * 8);
  gll16(g + 65536, l + 4096 + tid * 8);  // +64 rows
}

__device__ __forceinline__ bf16x8 fragld(const u16* h, int r, int slot) {
  return *(const bf16x8*)(h + r * 64 + ((slot ^ (r & 7)) << 3));
}

template <int MODE>
__global__ __launch_bounds__(512, 2) void gemm_k(
    const u16* __restrict__ A, const u16* __restrict__ Bt,
    const float* __restrict__ b0, const float* __restrict__ b1, const float* __restrict__ b2,
    u16* __restrict__ q_o, u16* __restrict__ k_o, u16* __restrict__ vt_o,
    const u16* __restrict__ xres, u16* __restrict__ y_o) {
  __shared__ u16 As[2][2][8192];
  __shared__ u16 Bs[2][2][8192];
  const int tid = threadIdx.x;
  const int wave = tid >> 6, lane = tid & 63;
  const int quad = lane >> 4, l16 = lane & 15;
  const int wr = wave >> 2, wc = wave & 3;
  const int bm = blockIdx.x, bn = blockIdx.y;
  const size_t arow = (size_t)bm * 256;
  const size_t brow = (size_t)bn * 256;

  const int r0 = tid >> 3;
  const int s8 = tid & 7;
  const int swz = (s8 ^ (r0 & 7)) << 3;  // inverse-swizzled source column
  const u16* gA = A + (arow + r0) * 1024 + swz;
  const u16* gB = Bt + (brow + r0) * 1024 + swz;

  f32x4 zero = {0.f, 0.f, 0.f, 0.f};
  f32x4 acc[8][4];
#pragma unroll
  for (int i = 0; i < 8; i++)
#pragma unroll
    for (int j = 0; j < 4; j++) acc[i][j] = zero;

  // prologue: T0 fully + T1.B halves; wait all but the 2 newest half-tiles (4 instrs)
  stage_half(gA, &As[0][0][0], tid);
  stage_half(gA + 131072, &As[0][1][0], tid);
  stage_half(gB, &Bs[0][0][0], tid);
  stage_half(gB + 131072, &Bs[0][1][0], tid);
  stage_half(gB + 64, &Bs[1][0][0], tid);
  stage_half(gB + 131072 + 64, &Bs[1][1][0], tid);
  WAITV(4);
  SBAR();

  const int bno = (wc & 1) * 64;
#pragma unroll 2
  for (int t = 0; t < 16; ++t) {
    const int cb = t & 1, nb = cb ^ 1;
    const u16* Ah = &As[cb][wr][0];
    const u16* Bh = &Bs[cb][wc >> 1][0];

    // all B frags for this tile (LDS reads of Bs[cb] happen only here)
    bf16x8 bfr[4][2];
#pragma unroll
    for (int n = 0; n < 4; n++)
#pragma unroll
      for (int ks = 0; ks < 2; ks++)
        bfr[n][ks] = fragld(Bh, bno + n * 16 + l16, ks * 4 + quad);

    // ---- first half: m0..3; stage (t+1).A ----
    {
      bf16x8 am[2][2];
#pragma unroll
      for (int m = 0; m < 2; m++)
#pragma unroll
        for (int ks = 0; ks < 2; ks++)
          am[m][ks] = fragld(Ah, m * 16 + l16, ks * 4 + quad);
      if (t < 15) stage_half(gA + (t + 1) * 64, &As[nb][0][0], tid);
      __builtin_amdgcn_s_setprio(1);
#pragma unroll
      for (int ks = 0; ks < 2; ks++)
#pragma unroll
        for (int m = 0; m < 2; m++)
#pragma unroll
          for (int n = 0; n < 4; n++) acc[m][n] = MFMA16(am[m][ks], bfr[n][ks], acc[m][n]);
      __builtin_amdgcn_s_setprio(0);
    }
    {
      bf16x8 am[2][2];
#pragma unroll
      for (int m = 0; m < 2; m++)
#pragma unroll
        for (int ks = 0; ks < 2; ks++)
          am[m][ks] = fragld(Ah, 32 + m * 16 + l16, ks * 4 + quad);
      if (t < 15) stage_half(gA + 131072 + (t + 1) * 64, &As[nb][1][0], tid);
      __builtin_amdgcn_s_setprio(1);
#pragma unroll
      for (int ks = 0; ks < 2; ks++)
#pragma unroll
        for (int m = 0; m < 2; m++)
#pragma unroll
          for (int n = 0; n < 4; n++) acc[2 + m][n] = MFMA16(am[m][ks], bfr[n][ks], acc[2 + m][n]);
      __builtin_amdgcn_s_setprio(0);
    }

    // mid-tile fence: all waves' B-reads served before Bs[cb] overwrite below.
    SBAR();
    __builtin_amdgcn_sched_barrier(0);

    // ---- second half: m4..7; stage (t+2).B into Bs[cb] ----
    {
      bf16x8 am[2][2];
#pragma unroll
      for (int m = 0; m < 2; m++)
#pragma unroll
        for (int ks = 0; ks < 2; ks++)
          am[m][ks] = fragld(Ah, 64 + m * 16 + l16, ks * 4 + quad);
      if (t < 14) stage_half(gB + (t + 2) * 64, &Bs[cb][0][0], tid);
      __builtin_amdgcn_s_setprio(1);
#pragma unroll
      for (int ks = 0; ks < 2; ks++)
#pragma unroll
        for (int m = 0; m < 2; m++)
#pragma unroll
          for (int n = 0; n < 4; n++) acc[4 + m][n] = MFMA16(am[m][ks], bfr[n][ks], acc[4 + m][n]);
      __builtin_amdgcn_s_setprio(0);
    }
    {
      bf16x8 am[2][2];
#pragma unroll
      for (int m = 0; m < 2; m++)
#pragma unroll
        for (int ks = 0; ks < 2; ks++)
          am[m][ks] = fragld(Ah, 96 + m * 16 + l16, ks * 4 + quad);
      if (t < 14) stage_half(gB + 131072 + (t + 2) * 64, &Bs[cb][1][0], tid);
      __builtin_amdgcn_s_setprio(1);
#pragma unroll
      for (int ks = 0; ks < 2; ks++)
#pragma unroll
        for (int m = 0; m < 2; m++)
#pragma unroll
          for (int n = 0; n < 4; n++) acc[6 + m][n] = MFMA16(am[m][ks], bfr[n][ks], acc[6 + m][n]);
      __builtin_amdgcn_s_setprio(0);
    }

    // K-tile boundary: next tile's A0,A1,B0,B1 landed; (t+2).B halves may stay in flight
    if (t < 14) {
      WAITV(4);
    } else if (t == 14) {
      WAITV(0);
    }
    SBAR();
  }

  if (MODE == 0) {
#pragma unroll
    for (int i = 0; i < 8; i++) {
      const int m0 = bm * 256 + wr * 128 + i * 16 + quad * 4;  // 4 consecutive tokens
      const int b = m0 >> 13, l0 = m0 & 8191;
      const int nch = l0 >> 8, c0 = l0 & 255;
#pragma unroll
      for (int j = 0; j < 4; j++) {
        const int n_g = bn * 256 + wc * 64 + j * 16 + l16;
        const int sec = n_g >> 10, e = n_g & 1023;
        const float* bias = (sec == 0) ? b0 : ((sec == 1) ? b1 : b2);
        const float be = bias[e];
        float v4[4];
#pragma unroll
        for (int r = 0; r < 4; r++) {
          float v = acc[i][j][r] + be;
          if (sec < 2) v = (v > 0.f) ? (v + 1.f) : __expf(v);
          v4[r] = v;
        }
        const int h = e >> 6, d = e & 63;
        const int bh = b * 16 + h;
        if (sec == 2) {
          u32x2 p;
          p.x = (u32)f2bf(v4[0]) | ((u32)f2bf(v4[1]) << 16);
          p.y = (u32)f2bf(v4[2]) | ((u32)f2bf(v4[3]) << 16);
          *(u32x2*)&vt_o[(((size_t)(bh * 32 + nch)) * 64 + d) * 256 + c0] = p;
        } else {
          u16* dst = (sec == 0) ? q_o : k_o;
          const size_t tb = (((size_t)bh * 8192 + l0) << 6) + d;
#pragma unroll
          for (int r = 0; r < 4; r++) dst[tb + (size_t)r * 64] = f2bf(v4[r]);
        }
      }
    }
  } else {
#pragma unroll
    for (int i = 0; i < 8; i++) {
#pragma unroll
      for (int j = 0; j < 4; j++) {
#pragma unroll
        for (int r = 0; r < 4; r++) {
          int m_g = bm * 256 + wr * 128 + i * 16 + quad * 4 + r;
          int n_g = bn * 256 + wc * 64 + j * 16 + l16;
          float v = acc[i][j][r] + b0[n_g] + bf2f(xres[(size_t)m_g * 1024 + n_g]);
          y_o[(size_t)m_g * 1024 + n_g] = f2bf(v);
        }
      }
    }
  }
}

// ---------------- phase A: per-chunk S^T = v^T k ([d2][d1]) and z = colsum k ----------------
__global__ __launch_bounds__(256, 2) void phaseA_k(const u16* __restrict__ kb, const u16* __restrict__ vt,
                                                   float* __restrict__ ST, float* __restrict__ zc) {
  __shared__ u16 kT[64 * 264];  // stride 264: rows 16B-aligned, b128 bank-spread (132 % 32 == 4)
  const int tid = threadIdx.x;
  const int wave = tid >> 6, lane = tid & 63;
  const int quad = lane >> 4, l16 = lane & 15;
  const int wr = wave >> 1, wc = wave & 1;
  const int bhn = blockIdx.x;
  const u16* kc = kb + (size_t)bhn * 16384;   // natural [c][d]
  const u16* vtc = vt + (size_t)bhn * 16384;  // transposed [d][c]

#pragma unroll
  for (int t = 0; t < 2; t++) {
    const int dblk = wave + 4 * t;
#pragma unroll
    for (int itc = 0; itc < 4; itc++) {
      const int c = itc * 64 + lane;
      bf16x8 kv = *(const bf16x8*)&kc[c * 64 + dblk * 8];
#pragma unroll
      for (int j = 0; j < 8; j++) kT[(dblk * 8 + j) * 264 + c] = (u16)kv[j];
    }
  }
  __syncthreads();

  f32x4 zero = {0.f, 0.f, 0.f, 0.f};
  f32x4 t4[2][2];
  f32x4 za[2];
#pragma unroll
  for (int i = 0; i < 2; i++) {
    za[i] = zero;
#pragma unroll
    for (int j = 0; j < 2; j++) t4[i][j] = zero;
  }
  bf16x8 ones;
#pragma unroll
  for (int j = 0; j < 8; j++) ones[j] = (short)0x3F80;

#pragma unroll
  for (int ks = 0; ks < 8; ks++) {
    bf16x8 av[2], bk2[2];
#pragma unroll
    for (int t = 0; t < 2; t++) av[t] = *(const bf16x8*)&vtc[(wr * 32 + t * 16 + l16) * 256 + ks * 32 + quad * 8];
#pragma unroll
    for (int t = 0; t < 2; t++) bk2[t] = *(const bf16x8*)&kT[(wc * 32 + t * 16 + l16) * 264 + ks * 32 + quad * 8];
#pragma unroll
    for (int i = 0; i < 2; i++)
#pragma unroll
      for (int j = 0; j < 2; j++) t4[i][j] = MFMA16(av[i], bk2[j], t4[i][j]);
    if (wr == 0) {
#pragma unroll
      for (int j = 0; j < 2; j++) za[j] = MFMA16(ones, bk2[j], za[j]);
    }
  }
  float* Sg = ST + (size_t)bhn * 4096;
#pragma unroll
  for (int i = 0; i < 2; i++)
#pragma unroll
    for (int j = 0; j < 2; j++)
#pragma unroll
      for (int r = 0; r < 4; r++)
        Sg[(wr * 32 + i * 16 + quad * 4 + r) * 64 + wc * 32 + j * 16 + l16] = t4[i][j][r];
  if (wr == 0 && quad == 0) {
#pragma unroll
    for (int j = 0; j < 2; j++) zc[(size_t)bhn * 64 + wc * 32 + j * 16 + l16] = za[j][0];
  }
}

// ---------------- phase B: exclusive prefix over chunks ----------------
__global__ __launch_bounds__(256) void phaseB_k(const float* __restrict__ ST, const float* __restrict__ zc,
                                                u16* __restrict__ STp, u16* __restrict__ zp) {
  const int blk = blockIdx.x, tid = threadIdx.x;
  if (blk < 512) {
    const int bh = blk >> 4;
    const int e = ((blk & 15) << 8) + tid;
    const size_t base = (size_t)bh * 32 * 4096 + e;
    float run = 0.f;
#pragma unroll
    for (int n = 0; n < 32; n++) {
      float v = ST[base + (size_t)n * 4096];
      STp[base + (size_t)n * 4096] = f2bf(run);
      run += v;
    }
  } else {
    const int idx = (blk - 512) * 256 + tid;
    const int bh = idx >> 6, d = idx & 63;
    const size_t zb = (size_t)bh * 2048 + d;
    float run = 0.f;
#pragma unroll
    for (int n = 0; n < 32; n++) {
      float v = zc[zb + n * 64];
      zp[zb + n * 64] = f2bf(run);
      run += v;
    }
  }
}

// ---------------- phase C: per-chunk output (R3-measured form, FROZEN) ----------------
// Two rebalance attempts (R6 chunk-pair serial: +7us, R8 wave-per-block: +27us) both lost
// to this form: 4-wave co-residency at 2 blocks/CU already hides the triangular idle,
// and splitting chunks destroys intra-block k/v L1 locality.
__global__ __launch_bounds__(256, 2) void phaseC_k(const u16* __restrict__ qb, const u16* __restrict__ kb,
                                                   const u16* __restrict__ vt, const u16* __restrict__ STp,
                                                   const u16* __restrict__ zp, u16* __restrict__ ao) {
  __shared__ u16 P[4][64 * 72];
  const int tid = threadIdx.x;
  const int wave = tid >> 6, lane = tid & 63;
  const int quad = lane >> 4, l16 = lane & 15;
  const int bhn = blockIdx.x;
  const int bh = bhn >> 5, n = bhn & 31;
  const int b = bh >> 4, h = bh & 15;
  const size_t cbase = (size_t)bhn * 16384;
  const u16* qc = qb + cbase;
  const u16* kc = kb + cbase;
  const u16* vtc = vt + cbase;
  const u16* STg = STp + (size_t)bhn * 4096;
  const u16* zg = zp + (size_t)bhn * 64;

  f32x4 zero = {0.f, 0.f, 0.f, 0.f};
  f32x4 num[4][4];
  f32x4 den[4];
#pragma unroll
  for (int i = 0; i < 4; i++) {
    den[i] = zero;
#pragma unroll
    for (int j = 0; j < 4; j++) num[i][j] = zero;
  }
  bf16x8 ones;
#pragma unroll
  for (int j = 0; j < 8; j++) ones[j] = (short)0x3F80;

  bf16x8 aq[4][2];
#pragma unroll
  for (int i = 0; i < 4; i++)
#pragma unroll
    for (int ks = 0; ks < 2; ks++)
      aq[i][ks] = *(const bf16x8*)&qc[(wave * 64 + i * 16 + l16) * 64 + ks * 32 + quad * 8];

#pragma unroll
  for (int ks = 0; ks < 2; ks++) {
    bf16x8 bz = *(const bf16x8*)&zg[ks * 32 + quad * 8];
    bf16x8 bs[4];
#pragma unroll
    for (int j = 0; j < 4; j++) bs[j] = *(const bf16x8*)&STg[(j * 16 + l16) * 64 + ks * 32 + quad * 8];
#pragma unroll
    for (int i = 0; i < 4; i++) {
      den[i] = MFMA16(aq[i][ks], bz, den[i]);
#pragma unroll
      for (int j = 0; j < 4; j++) num[i][j] = MFMA16(aq[i][ks], bs[j], num[i][j]);
    }
  }

  u16* Pw = &P[wave][0];

  for (int cc = 0; cc <= wave; cc++) {
    bf16x8 bkf[2][4];
#pragma unroll
    for (int ks = 0; ks < 2; ks++)
#pragma unroll
      for (int j = 0; j < 4; j++)
        bkf[ks][j] = *(const bf16x8*)&kc[(cc * 64 + j * 16 + l16) * 64 + ks * 32 + quad * 8];
#pragma unroll
    for (int i = 0; i < 4; i++) {
      f32x4 sc4[4];
#pragma unroll
      for (int j = 0; j < 4; j++) sc4[j] = zero;
#pragma unroll
      for (int ks = 0; ks < 2; ks++)
#pragma unroll
        for (int j = 0; j < 4; j++) sc4[j] = MFMA16(aq[i][ks], bkf[ks][j], sc4[j]);
#pragma unroll
      for (int j = 0; j < 4; j++) {
#pragma unroll
        for (int r = 0; r < 4; r++) {
          int row = wave * 64 + i * 16 + quad * 4 + r;
          int col = cc * 64 + j * 16 + l16;
          float v = (col <= row) ? sc4[j][r] : 0.f;
          Pw[(i * 16 + quad * 4 + r) * 72 + j * 16 + l16] = f2bf(v);
        }
      }
    }
    bf16x8 bvf[2][4];
#pragma unroll
    for (int ks2 = 0; ks2 < 2; ks2++)
#pragma unroll
      for (int j = 0; j < 4; j++)
        bvf[ks2][j] = *(const bf16x8*)&vtc[(j * 16 + l16) * 256 + cc * 64 + ks2 * 32 + quad * 8];
#pragma unroll
    for (int i = 0; i < 4; i++) {
#pragma unroll
      for (int ks2 = 0; ks2 < 2; ks2++) {
        bf16x8 ap = *(const bf16x8*)&Pw[(i * 16 + l16) * 72 + ks2 * 32 + quad * 8];
#pragma unroll
        for (int j = 0; j < 4; j++) num[i][j] = MFMA16(ap, bvf[ks2][j], num[i][j]);
        den[i] = MFMA16(ap, ones, den[i]);
      }
    }
  }

#pragma unroll
  for (int i = 0; i < 4; i++)
#pragma unroll
    for (int j = 0; j < 4; j++)
#pragma unroll
      for (int r = 0; r < 4; r++) {
        int row = wave * 64 + i * 16 + quad * 4 + r;
        int col = j * 16 + l16;
        float o = num[i][j][r] / (den[i][r] + 1e-6f);
        int l = n * 256 + row;
        ao[(((size_t)b * 8192 + l) * 16 + h) * 64 + col] = f2bf(o);
      }
}

// ---------------- LayerNorm (bf16 in, f32 out), 2 rows per block ----------------
__global__ __launch_bounds__(256) void ln_k(const u16* __restrict__ y, const float* __restrict__ gamma,
                                            const float* __restrict__ beta, float* __restrict__ o) {
  const int tid = threadIdx.x;
  const int wave = tid >> 6, lane = tid & 63;
  const float4 g = ((const float4*)gamma)[tid];
  const float4 bb = ((const float4*)beta)[tid];
  __shared__ float red[8];
#pragma unroll
  for (int rr = 0; rr < 2; rr++) {
    const int row = blockIdx.x * 2 + rr;
    u32x2 pv = ((const u32x2*)(y + (size_t)row * 1024))[tid];
    float vx = bf2f((u16)(pv.x & 0xFFFF)), vy = bf2f((u16)(pv.x >> 16));
    float vz = bf2f((u16)(pv.y & 0xFFFF)), vw = bf2f((u16)(pv.y >> 16));
    float s = vx + vy + vz + vw;
    float s2 = vx * vx + vy * vy + vz * vz + vw * vw;
#pragma unroll
    for (int off = 32; off; off >>= 1) {
      s += __shfl_down(s, off, 64);
      s2 += __shfl_down(s2, off, 64);
    }
    if (rr) __syncthreads();  // red[] reuse across rows
    if (lane == 0) { red[wave] = s; red[4 + wave] = s2; }
    __syncthreads();
    s = red[0] + red[1] + red[2] + red[3];
    s2 = red[4] + red[5] + red[6] + red[7];
    float mu = s * 0.0009765625f;
    float var = s2 * 0.0009765625f - mu * mu;
    float inv = rsqrtf(var + 1e-5f);
    float4 ov;
    ov.x = g.x * (vx - mu) * inv + bb.x;
    ov.y = g.y * (vy - mu) * inv + bb.y;
    ov.z = g.z * (vz - mu) * inv + bb.z;
    ov.w = g.w * (vw - mu) * inv + bb.w;
    ((float4*)(o + (size_t)row * 1024))[tid] = ov;
  }
}

extern "C" void kernel_launch(void* const* d_in, const int* in_sizes, int n_in,
                              void* d_out, int out_size, void* d_ws, size_t ws_size,
                              hipStream_t stream) {
  const float* x = (const float*)d_in[0];
  const float* Wq = (const float*)d_in[1];
  const float* bq = (const float*)d_in[2];
  const float* Wk = (const float*)d_in[3];
  const float* bk = (const float*)d_in[4];
  const float* Wv = (const float*)d_in[5];
  const float* bv = (const float*)d_in[6];
  const float* Wo = (const float*)d_in[7];
  const float* bo = (const float*)d_in[8];
  const float* gamma = (const float*)d_in[9];
  const float* beta = (const float*)d_in[10];

  char* ws = (char*)d_ws;
  u16* xb = (u16*)(ws + 0);                  // 33 MB (alive through gemm1: residual)
  u16* qb = (u16*)(ws + 33554432);           // 33 MB (dead after phaseC)
  u16* kb = (u16*)(ws + 67108864);           // 33 MB (dead after phaseC)
  u16* attno = (u16*)(ws + 100663296);       // 33 MB (phaseC out, gemm1 in)
  u16* vt = (u16*)(ws + 134217728);          // 33 MB (dead after phaseC)
  u16* wqkvT = (u16*)(ws + 167772160);       // 6 MB
  u16* woT = (u16*)(ws + 174063616);         // 2 MB
  float* SchT = (float*)(ws + 176160768);    // 16 MB
  float* zch = (float*)(ws + 192937984);     // 256 KB
  u16* STp = (u16*)(ws + 193200128);         // 8 MB
  u16* zp = (u16*)(ws + 201588736);          // 128 KB -> end 201719808
  u16* ypre = qb;                            // bf16 33 MB over qb (dead after phaseC)

  prep_k<<<8192, 256, 0, stream>>>(x, xb, Wq, Wk, Wv, Wo, wqkvT, woT);
  gemm_k<0><<<dim3(64, 12), 512, 0, stream>>>(xb, wqkvT, bq, bk, bv, qb, kb, vt, nullptr, nullptr);
  phaseA_k<<<1024, 256, 0, stream>>>(kb, vt, SchT, zch);
  phaseB_k<<<520, 256, 0, stream>>>(SchT, zch, STp, zp);
  phaseC_k<<<1024, 256, 0, stream>>>(qb, kb, vt, STp, zp, attno);
  gemm_k<1><<<dim3(64, 4), 512, 0, stream>>>(attno, woT, bo, nullptr, nullptr, nullptr, nullptr, nullptr, xb,
                                             ypre);
  ln_k<<<8192, 256, 0, stream>>>(ypre, gamma, beta, (float*)d_out);
}

// Round 10
// 357.163 us; speedup vs baseline: 1.0813x; 1.0083x over previous
//
#include <hip/hip_runtime.h>
#include <stdint.h>

typedef __attribute__((ext_vector_type(8))) short bf16x8;
typedef __attribute__((ext_vector_type(4))) float f32x4;
typedef __attribute__((ext_vector_type(2))) unsigned int u32x2;
typedef unsigned short u16;
typedef unsigned int u32;

#define MFMA16(a, b, c) __builtin_amdgcn_mfma_f32_16x16x32_bf16((a), (b), (c), 0, 0, 0)
// Builtin barrier: NO implicit waitcnt, NO memory clobber.
#define SBAR() __builtin_amdgcn_s_barrier()
#define WAITV(N) asm volatile("s_waitcnt vmcnt(" #N ")")

__device__ __forceinline__ u16 f2bf(float f) {
  union { float f; u32 u; } c; c.f = f;
  u32 u = c.u;
  return (u16)((u + 0x7FFFu + ((u >> 16) & 1u)) >> 16);
}

__device__ __forceinline__ float bf2f(u16 h) {
  union { u32 u; float f; } c;
  c.u = ((u32)h) << 16;
  return c.f;
}

__device__ __forceinline__ void gll16(const void* g, void* l) {
  __builtin_amdgcn_global_load_lds((__attribute__((address_space(1))) void*)(g),
                                   (__attribute__((address_space(3))) void*)(l),
                                   16, 0, 0);
}

// ---------------- prep (fused): cast x to bf16 + weight transpose ----------------
__global__ __launch_bounds__(256) void prep_k(const float* __restrict__ x, u16* __restrict__ xb,
                                              const float* __restrict__ Wq, const float* __restrict__ Wk,
                                              const float* __restrict__ Wv, const float* __restrict__ Wo,
                                              u16* __restrict__ wqkvT, u16* __restrict__ woT) {
  __shared__ float t[32][33];
  const int blk = blockIdx.x;
  if (blk < 4096) {
    int idx = blk * 256 + threadIdx.x;
#pragma unroll
    for (int it = 0; it < 4; it++) {
      size_t i = (size_t)idx + (size_t)it * 1048576;
      float4 v = ((const float4*)x)[i];
      u32x2 p;
      p.x = (u32)f2bf(v.x) | ((u32)f2bf(v.y) << 16);
      p.y = (u32)f2bf(v.z) | ((u32)f2bf(v.w) << 16);
      ((u32x2*)xb)[i] = p;
    }
  } else {
    const int wblk = blk - 4096;
    const int which = wblk >> 10;
    const int rem = wblk & 1023;
    const int k0 = (rem >> 5) * 32, n0 = (rem & 31) * 32;
    const float* W = (which == 0) ? Wq : (which == 1) ? Wk : (which == 2) ? Wv : Wo;
    int c = threadIdx.x & 31, r8 = threadIdx.x >> 5;
#pragma unroll
    for (int rr = 0; rr < 32; rr += 8)
      t[r8 + rr][c] = W[(size_t)(k0 + r8 + rr) * 1024 + n0 + c];
    __syncthreads();
    u16* outp = (which < 3) ? (wqkvT + (size_t)which * 1048576) : woT;
#pragma unroll
    for (int rr = 0; rr < 32; rr += 8)
      outp[(size_t)(n0 + r8 + rr) * 1024 + k0 + c] = f2bf(t[c][r8 + rr]);
  }
}

// ---------------- GEMM: 256x256 tile, BK=64, loose 2-barrier counted-vmcnt schedule ----------
// (R3/R6/R8/R9-measured structure: ~112 us gemm<0>, MfmaUtil 39%, 0 bank conflicts. FROZEN:
// 5 schedule variants (8-barrier, reg-pipeline, 1-barrier 3-buf) all measured worse.)
__device__ __forceinline__ void stage_half(const u16* g, u16* l, int tid) {
  gll16(g, l + tid * 8);
  gll16(g + 65536, l + 4096 + tid * 8);  // +64 rows
}

__device__ __forceinline__ bf16x8 fragld(const u16* h, int r, int slot) {
  return *(const bf16x8*)(h + r * 64 + ((slot ^ (r & 7)) << 3));
}

template <int MODE>
__global__ __launch_bounds__(512, 2) void gemm_k(
    const u16* __restrict__ A, const u16* __restrict__ Bt,
    const float* __restrict__ b0, const float* __restrict__ b1, const float* __restrict__ b2,
    u16* __restrict__ q_o, u16* __restrict__ k_o, u16* __restrict__ vt_o,
    const u16* __restrict__ xres, u16* __restrict__ y_o) {
  __shared__ u16 As[2][2][8192];
  __shared__ u16 Bs[2][2][8192];
  const int tid = threadIdx.x;
  const int wave = tid >> 6, lane = tid & 63;
  const int quad = lane >> 4, l16 = lane & 15;
  const int wr = wave >> 2, wc = wave & 3;
  const int bm = blockIdx.x, bn = blockIdx.y;
  const size_t arow = (size_t)bm * 256;
  const size_t brow = (size_t)bn * 256;

  const int r0 = tid >> 3;
  const int s8 = tid & 7;
  const int swz = (s8 ^ (r0 & 7)) << 3;  // inverse-swizzled source column
  const u16* gA = A + (arow + r0) * 1024 + swz;
  const u16* gB = Bt + (brow + r0) * 1024 + swz;

  f32x4 zero = {0.f, 0.f, 0.f, 0.f};
  f32x4 acc[8][4];
#pragma unroll
  for (int i = 0; i < 8; i++)
#pragma unroll
    for (int j = 0; j < 4; j++) acc[i][j] = zero;

  // prologue: T0 fully + T1.B halves; wait all but the 2 newest half-tiles (4 instrs)
  stage_half(gA, &As[0][0][0], tid);
  stage_half(gA + 131072, &As[0][1][0], tid);
  stage_half(gB, &Bs[0][0][0], tid);
  stage_half(gB + 131072, &Bs[0][1][0], tid);
  stage_half(gB + 64, &Bs[1][0][0], tid);
  stage_half(gB + 131072 + 64, &Bs[1][1][0], tid);
  WAITV(4);
  SBAR();

  const int bno = (wc & 1) * 64;
#pragma unroll 2
  for (int t = 0; t < 16; ++t) {
    const int cb = t & 1, nb = cb ^ 1;
    const u16* Ah = &As[cb][wr][0];
    const u16* Bh = &Bs[cb][wc >> 1][0];

    // all B frags for this tile (LDS reads of Bs[cb] happen only here)
    bf16x8 bfr[4][2];
#pragma unroll
    for (int n = 0; n < 4; n++)
#pragma unroll
      for (int ks = 0; ks < 2; ks++)
        bfr[n][ks] = fragld(Bh, bno + n * 16 + l16, ks * 4 + quad);

    // ---- first half: m0..3; stage (t+1).A ----
    {
      bf16x8 am[2][2];
#pragma unroll
      for (int m = 0; m < 2; m++)
#pragma unroll
        for (int ks = 0; ks < 2; ks++)
          am[m][ks] = fragld(Ah, m * 16 + l16, ks * 4 + quad);
      if (t < 15) stage_half(gA + (t + 1) * 64, &As[nb][0][0], tid);
      __builtin_amdgcn_s_setprio(1);
#pragma unroll
      for (int ks = 0; ks < 2; ks++)
#pragma unroll
        for (int m = 0; m < 2; m++)
#pragma unroll
          for (int n = 0; n < 4; n++) acc[m][n] = MFMA16(am[m][ks], bfr[n][ks], acc[m][n]);
      __builtin_amdgcn_s_setprio(0);
    }
    {
      bf16x8 am[2][2];
#pragma unroll
      for (int m = 0; m < 2; m++)
#pragma unroll
        for (int ks = 0; ks < 2; ks++)
          am[m][ks] = fragld(Ah, 32 + m * 16 + l16, ks * 4 + quad);
      if (t < 15) stage_half(gA + 131072 + (t + 1) * 64, &As[nb][1][0], tid);
      __builtin_amdgcn_s_setprio(1);
#pragma unroll
      for (int ks = 0; ks < 2; ks++)
#pragma unroll
        for (int m = 0; m < 2; m++)
#pragma unroll
          for (int n = 0; n < 4; n++) acc[2 + m][n] = MFMA16(am[m][ks], bfr[n][ks], acc[2 + m][n]);
      __builtin_amdgcn_s_setprio(0);
    }

    // mid-tile fence: all waves' B-reads served before Bs[cb] overwrite below.
    SBAR();
    __builtin_amdgcn_sched_barrier(0);

    // ---- second half: m4..7; stage (t+2).B into Bs[cb] ----
    {
      bf16x8 am[2][2];
#pragma unroll
      for (int m = 0; m < 2; m++)
#pragma unroll
        for (int ks = 0; ks < 2; ks++)
          am[m][ks] = fragld(Ah, 64 + m * 16 + l16, ks * 4 + quad);
      if (t < 14) stage_half(gB + (t + 2) * 64, &Bs[cb][0][0], tid);
      __builtin_amdgcn_s_setprio(1);
#pragma unroll
      for (int ks = 0; ks < 2; ks++)
#pragma unroll
        for (int m = 0; m < 2; m++)
#pragma unroll
          for (int n = 0; n < 4; n++) acc[4 + m][n] = MFMA16(am[m][ks], bfr[n][ks], acc[4 + m][n]);
      __builtin_amdgcn_s_setprio(0);
    }
    {
      bf16x8 am[2][2];
#pragma unroll
      for (int m = 0; m < 2; m++)
#pragma unroll
        for (int ks = 0; ks < 2; ks++)
          am[m][ks] = fragld(Ah, 96 + m * 16 + l16, ks * 4 + quad);
      if (t < 14) stage_half(gB + 131072 + (t + 2) * 64, &Bs[cb][1][0], tid);
      __builtin_amdgcn_s_setprio(1);
#pragma unroll
      for (int ks = 0; ks < 2; ks++)
#pragma unroll
        for (int m = 0; m < 2; m++)
#pragma unroll
          for (int n = 0; n < 4; n++) acc[6 + m][n] = MFMA16(am[m][ks], bfr[n][ks], acc[6 + m][n]);
      __builtin_amdgcn_s_setprio(0);
    }

    // K-tile boundary: next tile's A0,A1,B0,B1 landed; (t+2).B halves may stay in flight
    if (t < 14) {
      WAITV(4);
    } else if (t == 14) {
      WAITV(0);
    }
    SBAR();
  }

  if (MODE == 0) {
#pragma unroll
    for (int i = 0; i < 8; i++) {
      const int m0 = bm * 256 + wr * 128 + i * 16 + quad * 4;  // 4 consecutive tokens
      const int b = m0 >> 13, l0 = m0 & 8191;
      const int nch = l0 >> 8, c0 = l0 & 255;
#pragma unroll
      for (int j = 0; j < 4; j++) {
        const int n_g = bn * 256 + wc * 64 + j * 16 + l16;
        const int sec = n_g >> 10, e = n_g & 1023;
        const float* bias = (sec == 0) ? b0 : ((sec == 1) ? b1 : b2);
        const float be = bias[e];
        float v4[4];
#pragma unroll
        for (int r = 0; r < 4; r++) {
          float v = acc[i][j][r] + be;
          if (sec < 2) v = (v > 0.f) ? (v + 1.f) : __expf(v);
          v4[r] = v;
        }
        const int h = e >> 6, d = e & 63;
        const int bh = b * 16 + h;
        if (sec == 2) {
          u32x2 p;
          p.x = (u32)f2bf(v4[0]) | ((u32)f2bf(v4[1]) << 16);
          p.y = (u32)f2bf(v4[2]) | ((u32)f2bf(v4[3]) << 16);
          *(u32x2*)&vt_o[(((size_t)(bh * 32 + nch)) * 64 + d) * 256 + c0] = p;
        } else {
          u16* dst = (sec == 0) ? q_o : k_o;
          const size_t tb = (((size_t)bh * 8192 + l0) << 6) + d;
#pragma unroll
          for (int r = 0; r < 4; r++) dst[tb + (size_t)r * 64] = f2bf(v4[r]);
        }
      }
    }
  } else {
#pragma unroll
    for (int i = 0; i < 8; i++) {
#pragma unroll
      for (int j = 0; j < 4; j++) {
#pragma unroll
        for (int r = 0; r < 4; r++) {
          int m_g = bm * 256 + wr * 128 + i * 16 + quad * 4 + r;
          int n_g = bn * 256 + wc * 64 + j * 16 + l16;
          float v = acc[i][j][r] + b0[n_g] + bf2f(xres[(size_t)m_g * 1024 + n_g]);
          y_o[(size_t)m_g * 1024 + n_g] = f2bf(v);
        }
      }
    }
  }
}

// ---------------- phase A: per-chunk S^T = v^T k ([d2][d1]) and z = colsum k ----------------
__global__ __launch_bounds__(256, 2) void phaseA_k(const u16* __restrict__ kb, const u16* __restrict__ vt,
                                                   float* __restrict__ ST, float* __restrict__ zc) {
  __shared__ u16 kT[64 * 264];  // stride 264: rows 16B-aligned, b128 bank-spread (132 % 32 == 4)
  const int tid = threadIdx.x;
  const int wave = tid >> 6, lane = tid & 63;
  const int quad = lane >> 4, l16 = lane & 15;
  const int wr = wave >> 1, wc = wave & 1;
  const int bhn = blockIdx.x;
  const u16* kc = kb + (size_t)bhn * 16384;   // natural [c][d]
  const u16* vtc = vt + (size_t)bhn * 16384;  // transposed [d][c]

#pragma unroll
  for (int t = 0; t < 2; t++) {
    const int dblk = wave + 4 * t;
#pragma unroll
    for (int itc = 0; itc < 4; itc++) {
      const int c = itc * 64 + lane;
      bf16x8 kv = *(const bf16x8*)&kc[c * 64 + dblk * 8];
#pragma unroll
      for (int j = 0; j < 8; j++) kT[(dblk * 8 + j) * 264 + c] = (u16)kv[j];
    }
  }
  __syncthreads();

  f32x4 zero = {0.f, 0.f, 0.f, 0.f};
  f32x4 t4[2][2];
  f32x4 za[2];
#pragma unroll
  for (int i = 0; i < 2; i++) {
    za[i] = zero;
#pragma unroll
    for (int j = 0; j < 2; j++) t4[i][j] = zero;
  }
  bf16x8 ones;
#pragma unroll
  for (int j = 0; j < 8; j++) ones[j] = (short)0x3F80;

#pragma unroll
  for (int ks = 0; ks < 8; ks++) {
    bf16x8 av[2], bk2[2];
#pragma unroll
    for (int t = 0; t < 2; t++) av[t] = *(const bf16x8*)&vtc[(wr * 32 + t * 16 + l16) * 256 + ks * 32 + quad * 8];
#pragma unroll
    for (int t = 0; t < 2; t++) bk2[t] = *(const bf16x8*)&kT[(wc * 32 + t * 16 + l16) * 264 + ks * 32 + quad * 8];
#pragma unroll
    for (int i = 0; i < 2; i++)
#pragma unroll
      for (int j = 0; j < 2; j++) t4[i][j] = MFMA16(av[i], bk2[j], t4[i][j]);
    if (wr == 0) {
#pragma unroll
      for (int j = 0; j < 2; j++) za[j] = MFMA16(ones, bk2[j], za[j]);
    }
  }
  float* Sg = ST + (size_t)bhn * 4096;
#pragma unroll
  for (int i = 0; i < 2; i++)
#pragma unroll
    for (int j = 0; j < 2; j++)
#pragma unroll
      for (int r = 0; r < 4; r++)
        Sg[(wr * 32 + i * 16 + quad * 4 + r) * 64 + wc * 32 + j * 16 + l16] = t4[i][j][r];
  if (wr == 0 && quad == 0) {
#pragma unroll
    for (int j = 0; j < 2; j++) zc[(size_t)bhn * 64 + wc * 32 + j * 16 + l16] = za[j][0];
  }
}

// ---------------- phase B: exclusive prefix over chunks ----------------
__global__ __launch_bounds__(256) void phaseB_k(const float* __restrict__ ST, const float* __restrict__ zc,
                                                u16* __restrict__ STp, u16* __restrict__ zp) {
  const int blk = blockIdx.x, tid = threadIdx.x;
  if (blk < 512) {
    const int bh = blk >> 4;
    const int e = ((blk & 15) << 8) + tid;
    const size_t base = (size_t)bh * 32 * 4096 + e;
    float run = 0.f;
#pragma unroll
    for (int n = 0; n < 32; n++) {
      float v = ST[base + (size_t)n * 4096];
      STp[base + (size_t)n * 4096] = f2bf(run);
      run += v;
    }
  } else {
    const int idx = (blk - 512) * 256 + tid;
    const int bh = idx >> 6, d = idx & 63;
    const size_t zb = (size_t)bh * 2048 + d;
    float run = 0.f;
#pragma unroll
    for (int n = 0; n < 32; n++) {
      float v = zc[zb + n * 64];
      zp[zb + n * 64] = f2bf(run);
      run += v;
    }
  }
}

// ---------------- phase C: per-chunk output (R3-measured form, FROZEN) ----------------
__global__ __launch_bounds__(256, 2) void phaseC_k(const u16* __restrict__ qb, const u16* __restrict__ kb,
                                                   const u16* __restrict__ vt, const u16* __restrict__ STp,
                                                   const u16* __restrict__ zp, u16* __restrict__ ao) {
  __shared__ u16 P[4][64 * 72];
  const int tid = threadIdx.x;
  const int wave = tid >> 6, lane = tid & 63;
  const int quad = lane >> 4, l16 = lane & 15;
  const int bhn = blockIdx.x;
  const int bh = bhn >> 5, n = bhn & 31;
  const int b = bh >> 4, h = bh & 15;
  const size_t cbase = (size_t)bhn * 16384;
  const u16* qc = qb + cbase;
  const u16* kc = kb + cbase;
  const u16* vtc = vt + cbase;
  const u16* STg = STp + (size_t)bhn * 4096;
  const u16* zg = zp + (size_t)bhn * 64;

  f32x4 zero = {0.f, 0.f, 0.f, 0.f};
  f32x4 num[4][4];
  f32x4 den[4];
#pragma unroll
  for (int i = 0; i < 4; i++) {
    den[i] = zero;
#pragma unroll
    for (int j = 0; j < 4; j++) num[i][j] = zero;
  }
  bf16x8 ones;
#pragma unroll
  for (int j = 0; j < 8; j++) ones[j] = (short)0x3F80;

  bf16x8 aq[4][2];
#pragma unroll
  for (int i = 0; i < 4; i++)
#pragma unroll
    for (int ks = 0; ks < 2; ks++)
      aq[i][ks] = *(const bf16x8*)&qc[(wave * 64 + i * 16 + l16) * 64 + ks * 32 + quad * 8];

#pragma unroll
  for (int ks = 0; ks < 2; ks++) {
    bf16x8 bz = *(const bf16x8*)&zg[ks * 32 + quad * 8];
    bf16x8 bs[4];
#pragma unroll
    for (int j = 0; j < 4; j++) bs[j] = *(const bf16x8*)&STg[(j * 16 + l16) * 64 + ks * 32 + quad * 8];
#pragma unroll
    for (int i = 0; i < 4; i++) {
      den[i] = MFMA16(aq[i][ks], bz, den[i]);
#pragma unroll
      for (int j = 0; j < 4; j++) num[i][j] = MFMA16(aq[i][ks], bs[j], num[i][j]);
    }
  }

  u16* Pw = &P[wave][0];

  for (int cc = 0; cc <= wave; cc++) {
    bf16x8 bkf[2][4];
#pragma unroll
    for (int ks = 0; ks < 2; ks++)
#pragma unroll
      for (int j = 0; j < 4; j++)
        bkf[ks][j] = *(const bf16x8*)&kc[(cc * 64 + j * 16 + l16) * 64 + ks * 32 + quad * 8];
#pragma unroll
    for (int i = 0; i < 4; i++) {
      f32x4 sc4[4];
#pragma unroll
      for (int j = 0; j < 4; j++) sc4[j] = zero;
#pragma unroll
      for (int ks = 0; ks < 2; ks++)
#pragma unroll
        for (int j = 0; j < 4; j++) sc4[j] = MFMA16(aq[i][ks], bkf[ks][j], sc4[j]);
#pragma unroll
      for (int j = 0; j < 4; j++) {
#pragma unroll
        for (int r = 0; r < 4; r++) {
          int row = wave * 64 + i * 16 + quad * 4 + r;
          int col = cc * 64 + j * 16 + l16;
          float v = (col <= row) ? sc4[j][r] : 0.f;
          Pw[(i * 16 + quad * 4 + r) * 72 + j * 16 + l16] = f2bf(v);
        }
      }
    }
    bf16x8 bvf[2][4];
#pragma unroll
    for (int ks2 = 0; ks2 < 2; ks2++)
#pragma unroll
      for (int j = 0; j < 4; j++)
        bvf[ks2][j] = *(const bf16x8*)&vtc[(j * 16 + l16) * 256 + cc * 64 + ks2 * 32 + quad * 8];
#pragma unroll
    for (int i = 0; i < 4; i++) {
#pragma unroll
      for (int ks2 = 0; ks2 < 2; ks2++) {
        bf16x8 ap = *(const bf16x8*)&Pw[(i * 16 + l16) * 72 + ks2 * 32 + quad * 8];
#pragma unroll
        for (int j = 0; j < 4; j++) num[i][j] = MFMA16(ap, bvf[ks2][j], num[i][j]);
        den[i] = MFMA16(ap, ones, den[i]);
      }
    }
  }

#pragma unroll
  for (int i = 0; i < 4; i++)
#pragma unroll
    for (int j = 0; j < 4; j++)
#pragma unroll
      for (int r = 0; r < 4; r++) {
        int row = wave * 64 + i * 16 + quad * 4 + r;
        int col = j * 16 + l16;
        float o = num[i][j][r] / (den[i][r] + 1e-6f);
        int l = n * 256 + row;
        ao[(((size_t)b * 8192 + l) * 16 + h) * 64 + col] = f2bf(o);
      }
}

// ---------------- LayerNorm (bf16 in, f32 out), 2 rows per block ----------------
__global__ __launch_bounds__(256) void ln_k(const u16* __restrict__ y, const float* __restrict__ gamma,
                                            const float* __restrict__ beta, float* __restrict__ o) {
  const int tid = threadIdx.x;
  const int wave = tid >> 6, lane = tid & 63;
  const float4 g = ((const float4*)gamma)[tid];
  const float4 bb = ((const float4*)beta)[tid];
  __shared__ float red[8];
#pragma unroll
  for (int rr = 0; rr < 2; rr++) {
    const int row = blockIdx.x * 2 + rr;
    u32x2 pv = ((const u32x2*)(y + (size_t)row * 1024))[tid];
    float vx = bf2f((u16)(pv.x & 0xFFFF)), vy = bf2f((u16)(pv.x >> 16));
    float vz = bf2f((u16)(pv.y & 0xFFFF)), vw = bf2f((u16)(pv.y >> 16));
    float s = vx + vy + vz + vw;
    float s2 = vx * vx + vy * vy + vz * vz + vw * vw;
#pragma unroll
    for (int off = 32; off; off >>= 1) {
      s += __shfl_down(s, off, 64);
      s2 += __shfl_down(s2, off, 64);
    }
    if (rr) __syncthreads();  // red[] reuse across rows
    if (lane == 0) { red[wave] = s; red[4 + wave] = s2; }
    __syncthreads();
    s = red[0] + red[1] + red[2] + red[3];
    s2 = red[4] + red[5] + red[6] + red[7];
    float mu = s * 0.0009765625f;
    float var = s2 * 0.0009765625f - mu * mu;
    float inv = rsqrtf(var + 1e-5f);
    float4 ov;
    ov.x = g.x * (vx - mu) * inv + bb.x;
    ov.y = g.y * (vy - mu) * inv + bb.y;
    ov.z = g.z * (vz - mu) * inv + bb.z;
    ov.w = g.w * (vw - mu) * inv + bb.w;
    ((float4*)(o + (size_t)row * 1024))[tid] = ov;
  }
}

extern "C" void kernel_launch(void* const* d_in, const int* in_sizes, int n_in,
                              void* d_out, int out_size, void* d_ws, size_t ws_size,
                              hipStream_t stream) {
  const float* x = (const float*)d_in[0];
  const float* Wq = (const float*)d_in[1];
  const float* bq = (const float*)d_in[2];
  const float* Wk = (const float*)d_in[3];
  const float* bk = (const float*)d_in[4];
  const float* Wv = (const float*)d_in[5];
  const float* bv = (const float*)d_in[6];
  const float* Wo = (const float*)d_in[7];
  const float* bo = (const float*)d_in[8];
  const float* gamma = (const float*)d_in[9];
  const float* beta = (const float*)d_in[10];

  char* ws = (char*)d_ws;
  // Workspace plan (packed; SchT/zch overlay attno -- SchT/zch die at phaseB, attno is
  // written only later in phaseC; stream-sequential so lifetimes never overlap):
  u16* xb = (u16*)(ws + 0);                  // 33 MB (alive through gemm1: residual)
  u16* qb = (u16*)(ws + 33554432);           // 33 MB (dead after phaseC; ypre overlays)
  u16* kb = (u16*)(ws + 67108864);           // 33 MB (dead after phaseC)
  u16* attno = (u16*)(ws + 100663296);       // 33 MB (phaseC out, gemm1 in)
  float* SchT = (float*)(ws + 100663296);    // 16 MB  [overlay in attno region]
  float* zch = (float*)(ws + 117440512);     // 256 KB [overlay in attno region]
  u16* vt = (u16*)(ws + 134217728);          // 33 MB (dead after phaseC)
  u16* wqkvT = (u16*)(ws + 167772160);       // 6 MB
  u16* woT = (u16*)(ws + 174063616);         // 2 MB
  u16* STp = (u16*)(ws + 176160768);         // 8 MB (alive phaseB -> phaseC)
  u16* zp = (u16*)(ws + 184549376);          // 128 KB -> end ~184.7 MB (was 202)
  u16* ypre = qb;                            // bf16 33 MB over qb (dead after phaseC)

  prep_k<<<8192, 256, 0, stream>>>(x, xb, Wq, Wk, Wv, Wo, wqkvT, woT);
  gemm_k<0><<<dim3(64, 12), 512, 0, stream>>>(xb, wqkvT, bq, bk, bv, qb, kb, vt, nullptr, nullptr);
  phaseA_k<<<1024, 256, 0, stream>>>(kb, vt, SchT, zch);
  phaseB_k<<<520, 256, 0, stream>>>(SchT, zch, STp, zp);
  phaseC_k<<<1024, 256, 0, stream>>>(qb, kb, vt, STp, zp, attno);
  gemm_k<1><<<dim3(64, 4), 512, 0, stream>>>(attno, woT, bo, nullptr, nullptr, nullptr, nullptr, nullptr, xb,
                                             ypre);
  ln_k<<<8192, 256, 0, stream>>>(ypre, gamma, beta, (float*)d_out);
}